// Round 10
// baseline (326.708 us; speedup 1.0000x reference)
//
#include <hip/hip_runtime.h>
#include <stdint.h>

#define HID   1024
#define NHEAD 16
#define HDIM  64
#define NV    2048
#define NA    16
#define NTOK  2064
#define BSZ   2
#define MROWS 4128    // 4096 video + 32 action (valid rows)
#define MPAD  4224    // padded to 33*128 (rows 4128+ garbage, masked on output)
#define WSZ   1048576
// p = exp2(s * SCALE * log2(e) - 16)   [fixed-max softmax, exact after divide]
#define EXP_C1 0.18033688011112042f
#define EXP_C2 16.0f

// fragment-packed offsets: element (row r, col k) of a (16-row x 32-col) MFMA
// fragment tile stored lane-linear: lane = quad*16 + r15 reads 8 consecutive k.
#define POFF(r,k)  (((((r)>>4)*32  + ((k)>>5))*512) + ((((k)>>3)&3)*128) + (((r)&15)*8) + ((k)&7))   // 1024-col mats
#define QOFF(t,d)  (((((t)>>4)*2   + ((d)>>5))*512) + ((((d)>>3)&3)*128) + (((t)&15)*8) + ((d)&7))   // Q/K planes (64 col)
#define VOFF(d,ky) (((((d)>>4)*65  + ((ky)>>5))*512) + ((((ky)>>3)&3)*128) + (((d)&15)*8) + ((ky)&7)) // V^T planes (2080 keys padded)
#define QPLANE (129*2*512)    // 132096 elems per (b,h)
#define VPLANE (4*65*512)     // 133120 elems per (b,h)

typedef __bf16 bf16x8 __attribute__((ext_vector_type(8)));
typedef unsigned short u16x8 __attribute__((ext_vector_type(8)));
typedef unsigned short u16x4 __attribute__((ext_vector_type(4)));
typedef float f32x4 __attribute__((ext_vector_type(4)));

__device__ __forceinline__ unsigned short f2bf(float f) {  // RNE
  unsigned u = __builtin_bit_cast(unsigned, f);
  u += 0x7FFFu + ((u >> 16) & 1u);
  return (unsigned short)(u >> 16);
}
__device__ __forceinline__ unsigned short f2bf_trunc(float f) {
  return (unsigned short)(__builtin_bit_cast(unsigned, f) >> 16);
}
__device__ __forceinline__ unsigned pack2bf(float a, float b) {  // [lo=a, hi=b]
  return (__builtin_bit_cast(unsigned, a) >> 16) |
         (__builtin_bit_cast(unsigned, b) & 0xFFFF0000u);
}
__device__ __forceinline__ bf16x8 ldfrag(const unsigned short* p) {
  return __builtin_bit_cast(bf16x8, *(const u16x8*)p);
}

// ---------------------------------------------------------------------------
// Kernel 0: fp32 -> bf16 convert + fragment-pack.
// ---------------------------------------------------------------------------
__global__ __launch_bounds__(256) void cvt_kernel(
    const float* __restrict__ W0, const float* __restrict__ W1,
    const float* __restrict__ W2, const float* __restrict__ W3,
    const float* __restrict__ W4, const float* __restrict__ W5,
    const float* __restrict__ W6, const float* __restrict__ W7,
    const float* __restrict__ video, const float* __restrict__ action,
    unsigned short* __restrict__ Wb, unsigned short* __restrict__ Xp)
{
  const int y = blockIdx.y;
  const size_t idx = ((size_t)blockIdx.x * 256 + threadIdx.x) * 8;
  const float* src; unsigned short* dstbase; int row;
  if (y < 8) {
    const float* Ws[8] = {W0, W1, W2, W3, W4, W5, W6, W7};
    src = Ws[y] + idx; dstbase = Wb + (size_t)y * WSZ; row = (int)(idx >> 10);
  } else if (y < 12) {
    src = video + (size_t)(y - 8) * WSZ + idx; dstbase = Xp;
    row = ((y - 8) << 10) + (int)(idx >> 10);
  } else {
    if (idx >= (size_t)BSZ * NA * HID) return;
    src = action + idx; dstbase = Xp; row = 4096 + (int)(idx >> 10);
  }
  const int k0 = (int)(idx & 1023);
  float4 f0 = *(const float4*)src;
  float4 f1 = *(const float4*)(src + 4);
  u16x8 v;
  v[0]=f2bf(f0.x); v[1]=f2bf(f0.y); v[2]=f2bf(f0.z); v[3]=f2bf(f0.w);
  v[4]=f2bf(f1.x); v[5]=f2bf(f1.y); v[6]=f2bf(f1.z); v[7]=f2bf(f1.w);
  *(u16x8*)(dstbase + POFF(row, k0)) = v;
}

// row -> (batch, token) in the joint token space
__device__ __forceinline__ void row2bt(int rg, int& b, int& tok, bool& valid) {
  if (rg < 4096) { b = rg >> 11; tok = rg & 2047; valid = true; }
  else { int t = rg - 4096; b = t >> 4; tok = 2048 + (t & 15); valid = rg < MROWS; }
}

// ---------------------------------------------------------------------------
// Kernel 1: QKV GEMM — barrier/LDS-free reg-fragment GEMM, 512-thr blocks.
// grid (8 n, 3 z, 33 m); block = 8 waves, wave = 32m x 64n (acc[2][4]).
// launch_bounds(512,4): allow ~128 VGPR so the af/bf dbuf stays live.
// ---------------------------------------------------------------------------
__global__ __launch_bounds__(512, 4) void qkv_kernel(
    const unsigned short* __restrict__ Xp, const unsigned short* __restrict__ Wb,
    const float* __restrict__ bq, const float* __restrict__ bk,
    const float* __restrict__ bv, const float* __restrict__ bqa,
    const float* __restrict__ bka, const float* __restrict__ bva,
    unsigned short* __restrict__ Qpk, unsigned short* __restrict__ Kpk,
    unsigned short* __restrict__ Vpk)
{
  const int tid  = threadIdx.x;
  const int w    = tid >> 6;
  const int lane = tid & 63;
  const int quad = lane >> 4;
  const int l16  = lane & 15;
  const int mh   = w & 3;        // m quarter (32 rows)
  const int nh   = w >> 2;       // n half (64 cols)
  const int n0   = blockIdx.x * 128;
  const int z    = blockIdx.y;
  const int m0   = blockIdx.z * 128;
  const bool atile = (blockIdx.z == 32);

  const unsigned short* Wz = Wb + (size_t)(atile ? 3 + z : z) * WSZ;
  const float* bias = (z == 0) ? (atile ? bqa : bq)
                    : (z == 1) ? (atile ? bka : bk)
                               : (atile ? bva : bv);

  const int Mt = (m0 >> 4) + mh * 2;
  const int Nt = (n0 >> 4) + nh * 4;
  const unsigned short* pa = Xp + (size_t)Mt * 32 * 512 + lane * 8;
  const unsigned short* pb = Wz + (size_t)Nt * 32 * 512 + lane * 8;

  f32x4 acc[2][4] = {};
  bf16x8 af[2][2], bf[2][4];

#pragma unroll
  for (int mi = 0; mi < 2; mi++) af[0][mi] = ldfrag(pa + (size_t)(mi * 32) * 512);
#pragma unroll
  for (int ni = 0; ni < 4; ni++) bf[0][ni] = ldfrag(pb + (size_t)(ni * 32) * 512);

  for (int kt = 0; kt < 32; kt++) {
    const int cb = kt & 1, nb = cb ^ 1;
    if (kt < 31) {
#pragma unroll
      for (int mi = 0; mi < 2; mi++) af[nb][mi] = ldfrag(pa + (size_t)(mi * 32 + kt + 1) * 512);
#pragma unroll
      for (int ni = 0; ni < 4; ni++) bf[nb][ni] = ldfrag(pb + (size_t)(ni * 32 + kt + 1) * 512);
    }
#pragma unroll
    for (int mi = 0; mi < 2; mi++)
#pragma unroll
      for (int ni = 0; ni < 4; ni++)
        acc[mi][ni] = __builtin_amdgcn_mfma_f32_16x16x32_bf16(af[cb][mi], bf[cb][ni], acc[mi][ni], 0, 0, 0);
  }

  if (z < 2) {
    unsigned short* O = (z == 0) ? Qpk : Kpk;
#pragma unroll
    for (int mi = 0; mi < 2; mi++) {
      const int rgb = m0 + mh * 32 + mi * 16 + quad * 4;
#pragma unroll
      for (int ni = 0; ni < 4; ni++) {
        const int gcol = n0 + nh * 64 + ni * 16 + l16;
        const int head = gcol >> 6, col = gcol & 63;
        const float bias_v = bias[gcol];
        const int seg = (col >= 40) ? 2 : (col >= 20) ? 1 : 0;
        const int tin = col - seg * 20;
        const float om = exp2f(-(float)(tin >> 1) * 1.3287712379549449f);
        const bool evn = !(tin & 1);
#pragma unroll
        for (int r = 0; r < 4; r++) {
          int rg = rgb + r;
          int b, tok; bool valid;
          row2bt(rg, b, tok, valid);
          float val = acc[mi][ni][r] + bias_v;
          float part = __shfl_xor(val, 1);
          if (tok < 2048 && col < 60) {
            int dp = tok >> 8, hp = (tok >> 4) & 15, wp = tok & 15;
            float pos = (seg == 0) ? (float)dp : (seg == 1) ? (float)hp : (float)wp;
            float fr = pos * om;
            float cs = cosf(fr), sn = sinf(fr);
            val = evn ? (val * cs - part * sn) : (val * cs + part * sn);
          }
          if (valid)
            O[(size_t)(b * NHEAD + head) * QPLANE + QOFF(tok, col)] = f2bf(val);
        }
      }
    }
  } else {
#pragma unroll
    for (int mi = 0; mi < 2; mi++) {
      const int rgb = m0 + mh * 32 + mi * 16 + quad * 4;
      int b, tok; bool valid;
      row2bt(rgb, b, tok, valid);
#pragma unroll
      for (int ni = 0; ni < 4; ni++) {
        const int gcol = n0 + nh * 64 + ni * 16 + l16;
        const int head = gcol >> 6, d = gcol & 63;
        const float bias_v = bias[gcol];
        u16x4 pk;
#pragma unroll
        for (int r = 0; r < 4; r++) pk[r] = f2bf(acc[mi][ni][r] + bias_v);
        if (valid)
          *(u16x4*)&Vpk[(size_t)(b * NHEAD + head) * VPLANE + VOFF(d, tok)] = pk;
      }
    }
  }
}

// ---------------------------------------------------------------------------
// Kernel 2: flash attention — transposed-score (S^T = K Q^T), barrier-free,
// 512-thr blocks (8 waves x 16 q-rows = 128 q/block), launch_bounds(512,4)
// so kf/vf prefetch arrays stay live in registers (~128 VGPR budget).
// grid (32 bh, 17 q-groups); XCD-local K/V.
// ---------------------------------------------------------------------------
__global__ __launch_bounds__(512, 4) void attn_kernel(
    const unsigned short* __restrict__ Qpk,
    const unsigned short* __restrict__ Kpk,
    const unsigned short* __restrict__ Vpk,
    unsigned short* __restrict__ ctxp)
{
  __shared__ unsigned int Pt[8][2][64][4];   // [wave][c-frag][lane][dword] 16 KB

  const int tid  = threadIdx.x;
  const int wave = tid >> 6;
  const int lane = tid & 63;
  const int quad = lane >> 4;
  const int l16  = lane & 15;
  const int bh   = blockIdx.x;           // linear%8 == bh%8 -> XCD-local K/V
  const unsigned short* Qp = Qpk + (size_t)bh * QPLANE + lane * 8;
  const unsigned short* Kp = Kpk + (size_t)bh * QPLANE + lane * 8;
  const unsigned short* Vp = Vpk + (size_t)bh * VPLANE + lane * 8;

  const int qt = min(blockIdx.y * 8 + wave, 128);
  bf16x8 aq[2];   // B operand: n = query (lane&15), k = d
#pragma unroll
  for (int c = 0; c < 2; c++) aq[c] = ldfrag(Qp + (size_t)(qt * 2 + c) * 512);

  u16x8 ones_u;
#pragma unroll
  for (int i = 0; i < 8; i++) ones_u[i] = 0x3F80;
  const bf16x8 ones = __builtin_bit_cast(bf16x8, ones_u);

  f32x4 oacc[4] = {};   // O^T: per nt d-tile; m=d (quad*4+r), n=q (l16)
  f32x4 lacc = {};

  // iter-0 K and V fragments in flight
  bf16x8 kf[8], vf[8];
#pragma unroll
  for (int f = 0; f < 8; f++) kf[f] = ldfrag(Kp + (size_t)f * 512);
#pragma unroll
  for (int nt = 0; nt < 4; nt++)
#pragma unroll
    for (int c = 0; c < 2; c++) vf[nt * 2 + c] = ldfrag(Vp + (size_t)(nt * 65 + c) * 512);

  for (int it = 0; it < 32; it++) {
    // S^T = K Q^T : sacc[f] m=key (f*16+quad*4+r), n=q (l16)
    f32x4 sacc[4] = {};
#pragma unroll
    for (int f = 0; f < 4; f++)
#pragma unroll
      for (int c = 0; c < 2; c++)
        sacc[f] = __builtin_amdgcn_mfma_f32_16x16x32_bf16(kf[f * 2 + c], aq[c], sacc[f], 0, 0, 0);
    // refill kf for it+1
    if (it < 31) {
#pragma unroll
      for (int f = 0; f < 8; f++) kf[f] = ldfrag(Kp + (size_t)((it + 1) * 8 + f) * 512);
    }
    // exp + pack pairs + scatter into B-frag-packed LDS
#pragma unroll
    for (int f = 0; f < 4; f++) {
      float e0 = exp2f(__builtin_fmaf(sacc[f][0], EXP_C1, -EXP_C2));
      float e1 = exp2f(__builtin_fmaf(sacc[f][1], EXP_C1, -EXP_C2));
      float e2 = exp2f(__builtin_fmaf(sacc[f][2], EXP_C1, -EXP_C2));
      float e3 = exp2f(__builtin_fmaf(sacc[f][3], EXP_C1, -EXP_C2));
      const int c  = f >> 1;
      const int tq = (f & 1) * 2 + (quad >> 1);
      const int j0 = (quad & 1) * 2;
      uint2 w2; w2.x = pack2bf(e0, e1); w2.y = pack2bf(e2, e3);
      *(uint2*)&Pt[wave][c][tq * 16 + l16][j0] = w2;
    }
    // O^T += V^T P^T ; l += ones·P^T
#pragma unroll
    for (int c = 0; c < 2; c++) {
      bf16x8 ptf = __builtin_bit_cast(bf16x8, *(const u16x8*)&Pt[wave][c][lane][0]);
#pragma unroll
      for (int nt = 0; nt < 4; nt++)
        oacc[nt] = __builtin_amdgcn_mfma_f32_16x16x32_bf16(vf[nt * 2 + c], ptf, oacc[nt], 0, 0, 0);
      lacc = __builtin_amdgcn_mfma_f32_16x16x32_bf16(ones, ptf, lacc, 0, 0, 0);
    }
    // refill vf for it+1
    if (it < 31) {
#pragma unroll
      for (int nt = 0; nt < 4; nt++)
#pragma unroll
        for (int c = 0; c < 2; c++)
          vf[nt * 2 + c] = ldfrag(Vp + (size_t)(nt * 65 + (it + 1) * 2 + c) * 512);
    }
    __builtin_amdgcn_sched_barrier(0);  // keep refills in this iteration
  }

  // ---- tail: keys 2048..2063 (16 valid; V pad keys killed by P^T zeros) ----
  {
    f32x4 s0 = {};
#pragma unroll
    for (int c = 0; c < 2; c++) {
      bf16x8 bk = ldfrag(Kp + (size_t)(128 * 2 + c) * 512);
      s0 = __builtin_amdgcn_mfma_f32_16x16x32_bf16(bk, aq[c], s0, 0, 0, 0);
    }
    // zero the k=16..31 region of frag 0
    *(uint2*)&Pt[wave][0][32 + (lane >> 1)][(lane & 1) * 2] = make_uint2(0u, 0u);
    {
      float e0 = exp2f(__builtin_fmaf(s0[0], EXP_C1, -EXP_C2));
      float e1 = exp2f(__builtin_fmaf(s0[1], EXP_C1, -EXP_C2));
      float e2 = exp2f(__builtin_fmaf(s0[2], EXP_C1, -EXP_C2));
      float e3 = exp2f(__builtin_fmaf(s0[3], EXP_C1, -EXP_C2));
      const int tq = quad >> 1;
      const int j0 = (quad & 1) * 2;
      uint2 w2; w2.x = pack2bf(e0, e1); w2.y = pack2bf(e2, e3);
      *(uint2*)&Pt[wave][0][tq * 16 + l16][j0] = w2;
    }
    bf16x8 ptf = __builtin_bit_cast(bf16x8, *(const u16x8*)&Pt[wave][0][lane][0]);
#pragma unroll
    for (int nt = 0; nt < 4; nt++) {
      bf16x8 bv = ldfrag(Vp + (size_t)(nt * 65 + 64) * 512);
      oacc[nt] = __builtin_amdgcn_mfma_f32_16x16x32_bf16(bv, ptf, oacc[nt], 0, 0, 0);
    }
    lacc = __builtin_amdgcn_mfma_f32_16x16x32_bf16(ones, ptf, lacc, 0, 0, 0);
  }

  // epilogue: every lane's query is l16; l[q] broadcast in lacc rows
  const int b = bh >> 4, h = bh & 15;
  const float rl = 1.f / lacc[0];
  const int token = blockIdx.y * 128 + wave * 16 + l16;
  if (token < NTOK) {
    const int row = (token < 2048) ? (b * 2048 + token) : (4096 + b * NA + (token - 2048));
#pragma unroll
    for (int nt = 0; nt < 4; nt++) {
      const int col = h * HDIM + nt * 16 + quad * 4;   // + r
      u16x4 pk;
#pragma unroll
      for (int r = 0; r < 4; r++) pk[r] = f2bf(oacc[nt][r] * rl);
      *(u16x4*)&ctxp[POFF(row, col)] = pk;
    }
  }
}

// ---------------------------------------------------------------------------
// Kernel 3: output projection — 64x64 tiles, grid (16 n, 66 m) = 1056 blocks.
// ---------------------------------------------------------------------------
__global__ __launch_bounds__(256) void proj_kernel(
    const unsigned short* __restrict__ ctxp, const unsigned short* __restrict__ Wb,
    const float* __restrict__ bp, const float* __restrict__ bpa,
    float* __restrict__ out)
{
  const int tid  = threadIdx.x;
  const int w    = tid >> 6;
  const int lane = tid & 63;
  const int quad = lane >> 4;
  const int l16  = lane & 15;
  const int mh   = w & 1;
  const int nh   = w >> 1;
  const int m0   = blockIdx.y * 64;
  const int n0   = blockIdx.x * 64;
  const bool atile = (blockIdx.y >= 64);

  const unsigned short* Wz = Wb + (size_t)(atile ? 7 : 6) * WSZ;
  const float* bias = atile ? bpa : bp;

  const int Mt = (m0 >> 4) + mh * 2;
  const int Nt = (n0 >> 4) + nh * 2;
  const unsigned short* pa = ctxp + (size_t)Mt * 32 * 512 + lane * 8;
  const unsigned short* pb = Wz + (size_t)Nt * 32 * 512 + lane * 8;

  f32x4 acc[2][2] = {};
  bf16x8 af[2][2], bf[2][2];

#pragma unroll
  for (int mi = 0; mi < 2; mi++) af[0][mi] = ldfrag(pa + (size_t)(mi * 32) * 512);
#pragma unroll
  for (int ni = 0; ni < 2; ni++) bf[0][ni] = ldfrag(pb + (size_t)(ni * 32) * 512);

  for (int kt = 0; kt < 32; kt++) {
    const int cb = kt & 1, nb = cb ^ 1;
    if (kt < 31) {
#pragma unroll
      for (int mi = 0; mi < 2; mi++) af[nb][mi] = ldfrag(pa + (size_t)(mi * 32 + kt + 1) * 512);
#pragma unroll
      for (int ni = 0; ni < 2; ni++) bf[nb][ni] = ldfrag(pb + (size_t)(ni * 32 + kt + 1) * 512);
    }
#pragma unroll
    for (int mi = 0; mi < 2; mi++)
#pragma unroll
      for (int ni = 0; ni < 2; ni++)
        acc[mi][ni] = __builtin_amdgcn_mfma_f32_16x16x32_bf16(af[cb][mi], bf[cb][ni], acc[mi][ni], 0, 0, 0);
  }

#pragma unroll
  for (int mi = 0; mi < 2; mi++) {
    const int rgb = m0 + mh * 32 + mi * 16 + quad * 4;
#pragma unroll
    for (int ni = 0; ni < 2; ni++) {
      const int gcol = n0 + nh * 32 + ni * 16 + l16;
      const float bias_v = bias[gcol];
#pragma unroll
      for (int r = 0; r < 4; r++) {
        int rg = rgb + r;
        if (rg < MROWS) out[(size_t)rg * HID + gcol] = acc[mi][ni][r] + bias_v;
      }
    }
  }
}

// ---------------------------------------------------------------------------
extern "C" void kernel_launch(void* const* d_in, const int* in_sizes, int n_in,
                              void* d_out, int out_size, void* d_ws, size_t ws_size,
                              hipStream_t stream) {
  const float* A[18];
  if (in_sizes[0] == HID * HID) {
    for (int i = 0; i < 18; i++) A[i] = (const float*)d_in[i];
  } else {
    A[16] = (const float*)d_in[0];
    A[17] = (const float*)d_in[1];
    for (int i = 0; i < 16; i++) A[i] = (const float*)d_in[i + 2];
  }
  const float *Wq = A[0], *bq = A[1], *Wk = A[2], *bk = A[3], *Wv = A[4], *bv = A[5];
  const float *Wqa = A[6], *bqa = A[7], *Wka = A[8], *bka = A[9], *Wva = A[10], *bva = A[11];
  const float *Wp = A[12], *bp = A[13], *Wpa = A[14], *bpa = A[15];
  const float *video = A[16], *action = A[17];
  float* out = (float*)d_out;

  unsigned short* Wb   = (unsigned short*)d_ws;                 // 8 x 1M packed
  unsigned short* Xp   = Wb + (size_t)8 * WSZ;                  // MPAD x 1024 packed
  unsigned short* Qpk  = Xp + (size_t)(MPAD / 16) * 32 * 512;   // 32 planes
  unsigned short* Kpk  = Qpk + (size_t)32 * QPLANE;
  unsigned short* Vpk  = Kpk + (size_t)32 * QPLANE;
  unsigned short* ctxp = Vpk + (size_t)32 * VPLANE;             // MPAD x 1024 packed

  dim3 g0(512, 13);
  cvt_kernel<<<g0, 256, 0, stream>>>(Wq, Wk, Wv, Wqa, Wka, Wva, Wp, Wpa,
                                     video, action, Wb, Xp);
  dim3 g1(8, 3, 33);
  qkv_kernel<<<g1, 512, 0, stream>>>(Xp, Wb, bq, bk, bv, bqa, bka, bva,
                                     Qpk, Kpk, Vpk);
  dim3 g2(BSZ * NHEAD, 17);
  attn_kernel<<<g2, 512, 0, stream>>>(Qpk, Kpk, Vpk, ctxp);
  dim3 g3(16, 66);
  proj_kernel<<<g3, 256, 0, stream>>>(ctxp, Wb, bp, bpa, out);
}